// Round 3
// baseline (516.100 us; speedup 1.0000x reference)
//
#include <hip/hip_runtime.h>

// FlaxLinear irrep-wise linear. Round 3: lane-contiguous global loads
// (TA/coalescing fix), de-interleave via scalar LDS writes, XCD %8 swizzle
// so n-tile siblings share an XCD's L2. Epilogue unchanged (verified R2).

#define DTOT 4608
#define NMUL 512
#define BK 32
#define LDA 40                 // shorts per LDS row (80B)
#define APLANE (64 * LDA)      // 2560 shorts per irrep plane
#define NTHR 320               // 5 waves

typedef __attribute__((ext_vector_type(8))) short short8;
typedef __attribute__((ext_vector_type(4))) float float4v;

__device__ __forceinline__ unsigned short f2bf(float f) {
    return (unsigned short)((__builtin_bit_cast(unsigned int, f) + 0x8000u) >> 16);
}

template <int D>
__device__ __forceinline__ void gemm_body(
    int rel, const float* __restrict__ x, const float* __restrict__ W,
    const float* __restrict__ b0, float* __restrict__ out,
    unsigned short* As, unsigned short* Bs, float* Cs)
{
    constexpr int P     = (D == 1) ? 4 : D;      // compute waves
    constexpr int ROWS  = (D == 1) ? 256 : 64;   // rows per block
    constexpr int XOFF  = (D == 1) ? 0 : (D == 3 ? 512 : 2048);
    constexpr int SEG   = BK * D;                // floats per row per k-step
    constexpr int F4PR  = SEG / 4;               // float4s per row: 8/24/40
    constexpr int NF4   = ROWS * F4PR;           // 2048/1536/2560
    constexpr int NPASS = (NF4 + NTHR - 1) / NTHR;

    const int tid  = threadIdx.x;
    const int lane = tid & 63;
    const int w    = tid >> 6;
    const int lr   = lane & 15;
    const int lq   = lane >> 4;

    const int nt = rel & 7;
    const int mt = rel >> 3;
    const int n0 = nt * 64;
    const int m0 = mt * ROWS;

    const int bn  = tid & 63;
    const int bk0 = tid >> 6;

    float4v acc[4][4];
#pragma unroll
    for (int a = 0; a < 4; ++a)
#pragma unroll
        for (int b = 0; b < 4; ++b) acc[a][b] = (float4v)0.f;

    for (int kt = 0; kt < NMUL / BK; ++kt) {
        // ---- A staging: lane-contiguous float4 loads over the 16B-aligned
        //      region [64 rows x SEG floats]; de-interleave via b16 LDS writes ----
        const float* xk = x + XOFF + (size_t)kt * SEG;
#pragma unroll
        for (int p = 0; p < NPASS; ++p) {
            const int f = tid + p * NTHR;
            if ((NF4 % NTHR == 0) || f < NF4) {
                const int row = f / F4PR;
                const int c4  = f - row * F4PR;
                float4v v = *(const float4v*)(xk + (size_t)(m0 + row) * DTOT + c4 * 4);
                unsigned short* dst = As +
                    ((D == 1) ? ((row >> 6) * APLANE + (row & 63) * LDA) : (row * LDA));
#pragma unroll
                for (int j = 0; j < 4; ++j) {
                    const int c = c4 * 4 + j;
                    const int i = c % D;     // irrep
                    const int k = c / D;     // k within BK
                    if (D == 1) dst[k] = f2bf(v[j]);
                    else        dst[i * APLANE + k] = f2bf(v[j]);
                }
            }
        }
        // ---- B staging: Bs[n][k] = W[kt*32+k][n0+n]; lanes sweep n (coalesced) ----
        for (int k = bk0; k < BK; k += NTHR / 64) {
            Bs[bn * LDA + k] = f2bf(W[(size_t)(kt * BK + k) * NMUL + n0 + bn]);
        }
        __syncthreads();

        // ---- MFMA: wave w = its irrep plane (D=1: m-quarter), 4x4 of 16x16x32 ----
        if (w < P) {
            const unsigned short* Ap = As + w * APLANE;
            short8 afr[4], bfr[4];
#pragma unroll
            for (int mi = 0; mi < 4; ++mi)
                afr[mi] = *(const short8*)(Ap + (mi * 16 + lr) * LDA + lq * 8);
#pragma unroll
            for (int ni = 0; ni < 4; ++ni)
                bfr[ni] = *(const short8*)(Bs + (ni * 16 + lr) * LDA + lq * 8);
#pragma unroll
            for (int mi = 0; mi < 4; ++mi)
#pragma unroll
                for (int ni = 0; ni < 4; ++ni)
                    acc[mi][ni] = __builtin_amdgcn_mfma_f32_16x16x32_bf16(
                        afr[mi], bfr[ni], acc[mi][ni], 0, 0, 0);
        }
        __syncthreads();
    }

    const float PW = 0.044194173824159216f;  // 512^-0.5
    if (D == 1) {
        if (w < P) {
#pragma unroll
            for (int ni = 0; ni < 4; ++ni) {
                const int col = n0 + ni * 16 + lr;
                const float bias = b0[col];
#pragma unroll
                for (int mi = 0; mi < 4; ++mi)
#pragma unroll
                    for (int r = 0; r < 4; ++r)
                        out[(size_t)(m0 + w * 64 + mi * 16 + lq * 4 + r) * DTOT + col] =
                            acc[mi][ni][r] * PW + bias;
            }
        }
    } else {
        // route C through LDS -> contiguous 64*D-float output rows (verified R2)
#pragma unroll
        for (int mc = 0; mc < 4; ++mc) {
            if (w < P) {
#pragma unroll
                for (int ni = 0; ni < 4; ++ni)
#pragma unroll
                    for (int r = 0; r < 4; ++r)
                        Cs[(lq * 4 + r) * (64 * D) + (ni * 16 + lr) * D + w] =
                            acc[mc][ni][r] * PW;
            }
            __syncthreads();
            constexpr int F4 = 16 * 16 * D;
            for (int f = tid; f < F4; f += NTHR) {
                const int row = f / (16 * D);
                const int c4  = f % (16 * D);
                *(float4v*)(out + (size_t)(m0 + mc * 16 + row) * DTOT + XOFF + n0 * D + c4 * 4) =
                    *(const float4v*)(Cs + f * 4);
            }
            __syncthreads();
        }
    }
}

__global__ __launch_bounds__(NTHR) void flax_linear_kernel(
    const float* __restrict__ x, const float* __restrict__ w0,
    const float* __restrict__ w1, const float* __restrict__ w2,
    const float* __restrict__ b0, float* __restrict__ out)
{
    __shared__ __align__(16) unsigned char smem[25600];   // As planes / Cs union
    __shared__ __align__(16) unsigned short Bs[64 * LDA];
    unsigned short* As = (unsigned short*)smem;
    float* Cs = (float*)smem;

    int b = blockIdx.x;
    const float* Wsel;
    int kind;
    if (b < 512)       { kind = 5; Wsel = w2; }
    else if (b < 1024) { kind = 3; Wsel = w1; b -= 512; }
    else               { kind = 1; Wsel = w0; b -= 1024; }

    // XCD swizzle (assumes XCD = blockIdx % 8 round-robin): make all 8 n-tile
    // siblings of a row-panel share blockIdx%8 -> same XCD L2 caches the panel.
    const int nt = (b >> 3) & 7;
    const int mt = (b & 7) | ((b >> 6) << 3);
    const int rel = (mt << 3) | nt;

    if (kind == 5)      gemm_body<5>(rel, x, Wsel, b0, out, As, Bs, Cs);
    else if (kind == 3) gemm_body<3>(rel, x, Wsel, b0, out, As, Bs, Cs);
    else                gemm_body<1>(rel, x, Wsel, b0, out, As, Bs, Cs);
}

extern "C" void kernel_launch(void* const* d_in, const int* in_sizes, int n_in,
                              void* d_out, int out_size, void* d_ws, size_t ws_size,
                              hipStream_t stream) {
    const float* x  = (const float*)d_in[0];
    const float* w0 = (const float*)d_in[1];
    const float* w1 = (const float*)d_in[2];
    const float* w2 = (const float*)d_in[3];
    const float* b0 = (const float*)d_in[4];
    float* out = (float*)d_out;

    flax_linear_kernel<<<dim3(1152), dim3(NTHR), 0, stream>>>(x, w0, w1, w2, b0, out);
}

// Round 4
// 198.794 us; speedup vs baseline: 2.5962x; 2.5962x over previous
//
#include <hip/hip_runtime.h>

// Round 4: phase-separated. (1) deinterleave x -> 9 bf16 planes in ws,
// (2) convert+transpose W -> bf16 [n][k], (3) m97-replica bf16 GEMM with
// global_load_lds width-16 (per-channel planes, all accesses textbook),
// (4) reinterleave Y planes -> fp32 out (+bias). PW applied in GEMM epilogue.

#define BATCH 4096
#define DTOT 4608
#define NMUL 512

typedef __attribute__((ext_vector_type(8))) short short8;
typedef __attribute__((ext_vector_type(8))) unsigned short ushort8;
typedef __attribute__((ext_vector_type(4))) float float4v;

#define XPL_BYTES (9ull * BATCH * NMUL * 2)   // 37,748,736
#define WT_BYTES  (3ull * NMUL * NMUL * 2)    //  1,572,864
#define YPL_BYTES (9ull * BATCH * NMUL * 2)   // 37,748,736

__device__ __forceinline__ unsigned short f2bf(float f) {
    unsigned int u = __builtin_bit_cast(unsigned int, f);
    return (unsigned short)((u + 0x7fffu + ((u >> 16) & 1u)) >> 16);
}
__device__ __forceinline__ float bf2f(unsigned short h) {
    return __builtin_bit_cast(float, (unsigned int)h << 16);
}
__device__ __forceinline__ void gld16(const unsigned short* g, unsigned short* l) {
    __builtin_amdgcn_global_load_lds(
        (const __attribute__((address_space(1))) unsigned int*)(const void*)g,
        (__attribute__((address_space(3))) unsigned int*)(void*)l, 16, 0, 0);
}

// col -> (plane c, u) for the irrep-interleaved layout
__device__ __forceinline__ void colmap(int col, int& c, int& u) {
    if (col < 512)       { c = 0; u = col; }
    else if (col < 2048) { int t = col - 512;  c = 1 + t % 3; u = t / 3; }
    else                 { int t = col - 2048; c = 4 + t % 5; u = t / 5; }
}

// ---- phase 1: x[4096][4608] fp32 -> Xp[9][4096][512] bf16 ----
__global__ __launch_bounds__(256) void deint_x(const float* __restrict__ x,
                                               unsigned short* __restrict__ Xp) {
    const int row = blockIdx.x;
    __shared__ unsigned short buf[DTOT];
    const int tid = threadIdx.x;
    const float4v* src = (const float4v*)(x + (size_t)row * DTOT);
    for (int p = tid; p < DTOT / 4; p += 256) {
        float4v v = src[p];
#pragma unroll
        for (int j = 0; j < 4; ++j) {
            int c, u; colmap(p * 4 + j, c, u);
            buf[c * NMUL + u] = f2bf(v[j]);
        }
    }
    __syncthreads();
    for (int q = tid; q < DTOT / 8; q += 256) {           // 576 ushort8
        const int c = q >> 6, u8 = q & 63;
        *(ushort8*)(Xp + ((size_t)(c * BATCH + row) * NMUL) + u8 * 8) =
            *(const ushort8*)&buf[c * NMUL + u8 * 8];
    }
}

// ---- phase 2: W[k][n] fp32 -> Wt[ch][n][k] bf16 (64x64 tiles via LDS) ----
__global__ __launch_bounds__(256) void conv_w(const float* __restrict__ w0,
                                              const float* __restrict__ w1,
                                              const float* __restrict__ w2,
                                              unsigned short* __restrict__ Wt) {
    const int b = blockIdx.x;                 // 192 = 3 ch x 64 tiles
    const int ch = b >> 6, t = b & 63;
    const int tk = (t >> 3) * 64, tn = (t & 7) * 64;
    const float* W = (ch == 0) ? w0 : (ch == 1) ? w1 : w2;
    __shared__ unsigned short tile[64][72];
    const int tid = threadIdx.x;
    const int r0 = tid >> 4, c4 = (tid & 15) * 4;
#pragma unroll
    for (int rr = 0; rr < 4; ++rr) {
        const int row = r0 + rr * 16;         // k within tile
        float4v v = *(const float4v*)(W + (size_t)(tk + row) * NMUL + tn + c4);
#pragma unroll
        for (int j = 0; j < 4; ++j) tile[c4 + j][row] = f2bf(v[j]);  // transpose
    }
    __syncthreads();
    for (int q = tid; q < 512; q += 256) {    // 64 n-rows x 8 ushort8
        const int nn = q >> 3, k8 = q & 7;
        *(ushort8*)(Wt + ((size_t)(ch * NMUL + tn + nn) * NMUL) + tk + k8 * 8) =
            *(const ushort8*)&tile[nn][k8 * 8];
    }
}

// ---- phase 3: 9 x GEMM M=4096 K=512 N=512, m97-style ----
__global__ __launch_bounds__(256) void gemm_k(const unsigned short* __restrict__ Xp,
                                              const unsigned short* __restrict__ Wt,
                                              unsigned short* __restrict__ Yp,
                                              float* __restrict__ out,
                                              const float* __restrict__ b0,
                                              int use_y) {
    const int c = blockIdx.z;
    const int wch = (c == 0) ? 0 : (c < 4 ? 1 : 2);
    const int n0 = blockIdx.x * 128;
    const int m0 = blockIdx.y * 128;

    const unsigned short* A  = Xp + (size_t)c * BATCH * NMUL;
    const unsigned short* Bm = Wt + (size_t)wch * NMUL * NMUL;

    __shared__ unsigned short As[128 * 32];   // [row][k], unpadded (global_load_lds)
    __shared__ unsigned short Bs[128 * 32];   // [n][k]

    const int tid = threadIdx.x;
    const int lane = tid & 63;
    const int w = tid >> 6;
    const int lr = lane & 15;
    const int lq = lane >> 4;
    const int wm = (w >> 1) * 64;
    const int wn = (w & 1) * 64;

    const int srow = lane >> 2;               // staging: row-within-16
    const int scol = (lane & 3) * 8;          // elems (16 B)

    const unsigned short* Ag = A + (size_t)(m0 + w * 32 + srow) * NMUL + scol;
    const unsigned short* Bg = Bm + (size_t)(n0 + w * 32 + srow) * NMUL + scol;
    unsigned short* Al = As + w * 1024;       // wave-uniform LDS base
    unsigned short* Bl = Bs + w * 1024;

    float4v acc[4][4];
#pragma unroll
    for (int a = 0; a < 4; ++a)
#pragma unroll
        for (int b = 0; b < 4; ++b) acc[a][b] = (float4v)0.f;

    for (int kt = 0; kt < 16; ++kt) {
        const int ko = kt * 32;
        gld16(Ag + ko, Al);
        gld16(Ag + ko + 16 * NMUL, Al + 512);
        gld16(Bg + ko, Bl);
        gld16(Bg + ko + 16 * NMUL, Bl + 512);
        __syncthreads();
        short8 af[4], bf[4];
#pragma unroll
        for (int mi = 0; mi < 4; ++mi)
            af[mi] = *(const short8*)(As + (wm + mi * 16 + lr) * 32 + lq * 8);
#pragma unroll
        for (int ni = 0; ni < 4; ++ni)
            bf[ni] = *(const short8*)(Bs + (wn + ni * 16 + lr) * 32 + lq * 8);
#pragma unroll
        for (int mi = 0; mi < 4; ++mi)
#pragma unroll
            for (int ni = 0; ni < 4; ++ni)
                acc[mi][ni] = __builtin_amdgcn_mfma_f32_16x16x32_bf16(
                    af[mi], bf[ni], acc[mi][ni], 0, 0, 0);
        __syncthreads();
    }

    const float PW = 0.044194173824159216f;   // 512^-0.5
    if (use_y) {
        unsigned short* Y = Yp + (size_t)c * BATCH * NMUL;
#pragma unroll
        for (int mi = 0; mi < 4; ++mi)
#pragma unroll
            for (int ni = 0; ni < 4; ++ni)
#pragma unroll
                for (int r = 0; r < 4; ++r)
                    Y[(size_t)(m0 + wm + mi * 16 + lq * 4 + r) * NMUL +
                      n0 + wn + ni * 16 + lr] = f2bf(acc[mi][ni][r] * PW);
    } else {
        const int d    = (c == 0) ? 1 : (c < 4 ? 3 : 5);
        const int xoff = (c == 0) ? 0 : (c < 4 ? 512 : 2048);
        const int irr  = (c == 0) ? 0 : (c < 4 ? c - 1 : c - 4);
#pragma unroll
        for (int ni = 0; ni < 4; ++ni) {
            const int col = n0 + wn + ni * 16 + lr;
            const float bias = (c == 0) ? b0[col] : 0.f;
#pragma unroll
            for (int mi = 0; mi < 4; ++mi)
#pragma unroll
                for (int r = 0; r < 4; ++r)
                    out[(size_t)(m0 + wm + mi * 16 + lq * 4 + r) * DTOT +
                        xoff + col * d + irr] = acc[mi][ni][r] * PW + bias;
        }
    }
}

// ---- phase 4: Yp[9][4096][512] bf16 -> out[4096][4608] fp32 (+bias on 0e) ----
__global__ __launch_bounds__(256) void inter_y(const unsigned short* __restrict__ Yp,
                                               const float* __restrict__ b0,
                                               float* __restrict__ out) {
    const int row = blockIdx.x;
    __shared__ unsigned short buf[DTOT];
    const int tid = threadIdx.x;
    for (int q = tid; q < DTOT / 8; q += 256) {
        const int c = q >> 6, u8 = q & 63;
        *(ushort8*)&buf[c * NMUL + u8 * 8] =
            *(const ushort8*)(Yp + ((size_t)(c * BATCH + row) * NMUL) + u8 * 8);
    }
    __syncthreads();
    float4v* dst = (float4v*)(out + (size_t)row * DTOT);
    for (int p = tid; p < DTOT / 4; p += 256) {
        float4v v;
#pragma unroll
        for (int j = 0; j < 4; ++j) {
            const int col = p * 4 + j;
            int c, u; colmap(col, c, u);
            float f = bf2f(buf[c * NMUL + u]);
            if (col < 512) f += b0[col];
            v[j] = f;
        }
        dst[p] = v;
    }
}

extern "C" void kernel_launch(void* const* d_in, const int* in_sizes, int n_in,
                              void* d_out, int out_size, void* d_ws, size_t ws_size,
                              hipStream_t stream) {
    const float* x  = (const float*)d_in[0];
    const float* w0 = (const float*)d_in[1];
    const float* w1 = (const float*)d_in[2];
    const float* w2 = (const float*)d_in[3];
    const float* b0 = (const float*)d_in[4];
    float* out = (float*)d_out;

    unsigned short* Xp = (unsigned short*)d_ws;
    unsigned short* Wt = (unsigned short*)((char*)d_ws + XPL_BYTES);
    unsigned short* Yp = (unsigned short*)((char*)d_ws + XPL_BYTES + WT_BYTES);
    const int use_y = (ws_size >= XPL_BYTES + WT_BYTES + YPL_BYTES) ? 1 : 0;

    deint_x<<<dim3(BATCH), dim3(256), 0, stream>>>(x, Xp);
    conv_w<<<dim3(192), dim3(256), 0, stream>>>(w0, w1, w2, Wt);
    gemm_k<<<dim3(4, 32, 9), dim3(256), 0, stream>>>(Xp, Wt, Yp, out, b0, use_y);
    if (use_y)
        inter_y<<<dim3(BATCH), dim3(256), 0, stream>>>(Yp, b0, out);
}